// Round 1
// baseline (27353.192 us; speedup 1.0000x reference)
//
#include <hip/hip_runtime.h>

#define DIM 128
#define N_USERS 200000
#define N_ITEMS 100000

// ---------------------------------------------------------------------------
// SpMM: out[rows[e]] += vals[e] * x[cols[e]]   (out zeroed beforehand)
// 32 threads per edge, float4 per thread: 512B coalesced gather per edge.
// ---------------------------------------------------------------------------
__global__ __launch_bounds__(256) void spmm_atomic_kernel(
    const int* __restrict__ rows, const int* __restrict__ cols,
    const float* __restrict__ vals, const float* __restrict__ x,
    float* __restrict__ out, int nnz)
{
    long long t = (long long)blockIdx.x * blockDim.x + threadIdx.x;
    int e    = (int)(t >> 5);
    int lane = (int)(t & 31);
    if (e >= nnz) return;
    int r = rows[e];
    int c = cols[e];
    float v = vals[e];
    const float4 xv = *reinterpret_cast<const float4*>(x + (size_t)c * DIM + lane * 4);
    float* o = out + (size_t)r * DIM + lane * 4;
    unsafeAtomicAdd(o + 0, v * xv.x);
    unsafeAtomicAdd(o + 1, v * xv.y);
    unsafeAtomicAdd(o + 2, v * xv.z);
    unsafeAtomicAdd(o + 3, v * xv.w);
}

// ---------------------------------------------------------------------------
// Fused: out = relu( concat([ho, cur], axis=1) @ W + b )
//   ho, cur: [M, 128]  W: [256, 128]  b: [128]  out: [M, 128]
// Block: 256 threads, tile 64 rows x 128 cols, k-blocked by 64.
// kb = 0,1 read ho (cols 0..127); kb = 2,3 read cur.
// Safe for out == ho: each block reads all its A-tiles before storing,
// and blocks only write their own rows.
// ---------------------------------------------------------------------------
__global__ __launch_bounds__(256) void fused_gemm_relu_kernel(
    const float* __restrict__ HO, const float* __restrict__ CUR,
    const float* __restrict__ W, const float* __restrict__ bias,
    float* __restrict__ out, int M)
{
    __shared__ float As[64][64];
    __shared__ float Ws[64][128];

    int tid  = threadIdx.x;
    int row0 = blockIdx.x * 64;

    int cx = tid & 31;   // col group: cols cx*4 .. cx*4+3
    int ry = tid >> 5;   // row group: rows ry*8 .. ry*8+7

    float4 acc[8];
#pragma unroll
    for (int i = 0; i < 8; ++i) acc[i] = make_float4(0.f, 0.f, 0.f, 0.f);

    for (int kb = 0; kb < 4; ++kb) {
        const float* src = (kb < 2) ? HO : CUR;
        int colbase = (kb & 1) * 64;

        // load A tile: 64 rows x 64 cols
        {
            int r  = tid >> 4;   // 0..15
            int c4 = tid & 15;   // 0..15
#pragma unroll
            for (int it = 0; it < 4; ++it) {
                int rr   = r + it * 16;
                int grow = row0 + rr;
                float4 v = make_float4(0.f, 0.f, 0.f, 0.f);
                if (grow < M)
                    v = *reinterpret_cast<const float4*>(
                        src + (size_t)grow * DIM + colbase + c4 * 4);
                *reinterpret_cast<float4*>(&As[rr][c4 * 4]) = v;
            }
        }
        // load W tile: 64 rows x 128 cols
        {
            int r  = tid >> 5;   // 0..7
            int c4 = tid & 31;   // 0..31
#pragma unroll
            for (int it = 0; it < 8; ++it) {
                int rr = r + it * 8;
                float4 v = *reinterpret_cast<const float4*>(
                    W + (size_t)(kb * 64 + rr) * DIM + c4 * 4);
                *reinterpret_cast<float4*>(&Ws[rr][c4 * 4]) = v;
            }
        }
        __syncthreads();

#pragma unroll 16
        for (int k = 0; k < 64; ++k) {
            float4 wv = *reinterpret_cast<const float4*>(&Ws[k][cx * 4]);
#pragma unroll
            for (int i = 0; i < 8; ++i) {
                float a = As[ry * 8 + i][k];
                acc[i].x += a * wv.x;
                acc[i].y += a * wv.y;
                acc[i].z += a * wv.z;
                acc[i].w += a * wv.w;
            }
        }
        __syncthreads();
    }

    float4 bv = *reinterpret_cast<const float4*>(bias + cx * 4);
#pragma unroll
    for (int i = 0; i < 8; ++i) {
        int grow = row0 + ry * 8 + i;
        if (grow < M) {
            float4 r;
            r.x = fmaxf(acc[i].x + bv.x, 0.f);
            r.y = fmaxf(acc[i].y + bv.y, 0.f);
            r.z = fmaxf(acc[i].z + bv.z, 0.f);
            r.w = fmaxf(acc[i].w + bv.w, 0.f);
            *reinterpret_cast<float4*>(out + (size_t)grow * DIM + cx * 4) = r;
        }
    }
}

extern "C" void kernel_launch(void* const* d_in, const int* in_sizes, int n_in,
                              void* d_out, int out_size, void* d_ws, size_t ws_size,
                              hipStream_t stream) {
    const float* ufea    = (const float*)d_in[0];
    const float* vfea    = (const float*)d_in[1];
    const int*   uv_rows = (const int*)d_in[2];
    const int*   uv_cols = (const int*)d_in[3];
    const float* uv_vals = (const float*)d_in[4];
    const int*   vu_rows = (const int*)d_in[5];
    const int*   vu_cols = (const int*)d_in[6];
    const float* vu_vals = (const float*)d_in[7];
    const float* user_W  = (const float*)d_in[8];   // [2, 256, 128]
    const float* user_b  = (const float*)d_in[9];   // [2, 128]
    const float* item_W  = (const float*)d_in[10];
    const float* item_b  = (const float*)d_in[11];

    const int nnz = in_sizes[2];

    float* out_user = (float*)d_out;                       // [U,128]
    float* out_item = out_user + (size_t)N_USERS * DIM;    // [I,128]

    const size_t UD = (size_t)N_USERS * DIM;   // 25.6M floats
    const size_t ID = (size_t)N_ITEMS * DIM;   // 12.8M floats

    float* U0 = (float*)d_ws;
    float* U1 = U0 + UD;
    float* V0 = U1 + UD;
    float* V1 = V0 + ID;
    float* V2 = V1 + ID;   // total 89.6M floats = 358.4 MB

    auto spmm = [&](const int* r, const int* c, const float* v,
                    const float* x, float* out, size_t outElems) {
        hipMemsetAsync(out, 0, outElems * sizeof(float), stream);
        long long total = (long long)nnz * 32;
        int blocks = (int)((total + 255) / 256);
        spmm_atomic_kernel<<<blocks, 256, 0, stream>>>(r, c, v, x, out, nnz);
    };
    auto gemm = [&](const float* ho, const float* cur, const float* Wl,
                    const float* bl, float* out, int M) {
        fused_gemm_relu_kernel<<<(M + 63) / 64, 256, 0, stream>>>(ho, cur, Wl, bl, out, M);
    };

    // ---------------- layer 0 (cur_u = ufea, cur_v = vfea) ----------------
    spmm(vu_rows, vu_cols, vu_vals, ufea, V0, ID);   // TI  = spmm(vu, cur_u)  [I]
    spmm(uv_rows, uv_cols, uv_vals, vfea, U0, UD);   // TU  = spmm(uv, cur_v)  [U]
    spmm(vu_rows, vu_cols, vu_vals, U0,   V1, ID);   // HV  = spmm(vu, TU)     [I]
    spmm(uv_rows, uv_cols, uv_vals, V0,   U0, UD);   // HU  = spmm(uv, TI)     [U]
    gemm(U0, ufea, user_W,                user_b,       U0, N_USERS);  // new_u (in-place)
    gemm(V1, vfea, item_W,                item_b,       V1, N_ITEMS);  // new_v (in-place)

    // ---------------- layer 1 (cur_u = U0, cur_v = V1) --------------------
    spmm(vu_rows, vu_cols, vu_vals, U0, V0, ID);     // TI'
    spmm(uv_rows, uv_cols, uv_vals, V1, U1, UD);     // TU'
    spmm(vu_rows, vu_cols, vu_vals, U1, V2, ID);     // HV'
    spmm(uv_rows, uv_cols, uv_vals, V0, U1, UD);     // HU'
    gemm(U1, U0, user_W + 2 * DIM * DIM, user_b + DIM, out_user, N_USERS);
    gemm(V2, V1, item_W + 2 * DIM * DIM, item_b + DIM, out_item, N_ITEMS);
}

// Round 2
// 2308.361 us; speedup vs baseline: 11.8496x; 11.8496x over previous
//
#include <hip/hip_runtime.h>

#define DIM 128
#define N_USERS 200000
#define N_ITEMS 100000

// ===========================================================================
// CSR build: histogram -> 3-phase exclusive scan -> scatter
// ===========================================================================

__global__ __launch_bounds__(256) void hist_kernel(
    const int* __restrict__ rows, int* __restrict__ counts, int nnz)
{
    int e = blockIdx.x * blockDim.x + threadIdx.x;
    if (e < nnz) atomicAdd(&counts[rows[e]], 1);
}

// scan1: per-block inclusive scan of 1024 elems; out[i+1] = inclusive within
// block; blockSums[b] = block total; out[0] = 0.
__global__ __launch_bounds__(256) void scan1_kernel(
    const int* __restrict__ in, int* __restrict__ out,
    int* __restrict__ blockSums, int n)
{
    __shared__ int lds[256];
    int tid  = threadIdx.x;
    int base = blockIdx.x * 1024 + tid * 4;
    int v0 = (base + 0 < n) ? in[base + 0] : 0;
    int v1 = (base + 1 < n) ? in[base + 1] : 0;
    int v2 = (base + 2 < n) ? in[base + 2] : 0;
    int v3 = (base + 3 < n) ? in[base + 3] : 0;
    int s1 = v0 + v1, s2 = s1 + v2, s3 = s2 + v3;
    lds[tid] = s3;
    __syncthreads();
    for (int d = 1; d < 256; d <<= 1) {
        int t = 0;
        if (tid >= d) t = lds[tid - d];
        __syncthreads();
        lds[tid] += t;
        __syncthreads();
    }
    int excl = (tid > 0) ? lds[tid - 1] : 0;
    if (base + 0 < n) out[base + 1] = excl + v0;
    if (base + 1 < n) out[base + 2] = excl + s1;
    if (base + 2 < n) out[base + 3] = excl + s2;
    if (base + 3 < n) out[base + 4] = excl + s3;
    if (tid == 255) blockSums[blockIdx.x] = lds[255];
    if (blockIdx.x == 0 && tid == 0) out[0] = 0;
}

// scan2: single block, exclusive scan of blockSums (nb <= 1024)
__global__ __launch_bounds__(256) void scan2_kernel(int* __restrict__ bs, int nb)
{
    __shared__ int lds[256];
    int tid  = threadIdx.x;
    int base = tid * 4;
    int v0 = (base + 0 < nb) ? bs[base + 0] : 0;
    int v1 = (base + 1 < nb) ? bs[base + 1] : 0;
    int v2 = (base + 2 < nb) ? bs[base + 2] : 0;
    int v3 = (base + 3 < nb) ? bs[base + 3] : 0;
    int s1 = v0 + v1, s2 = s1 + v2, s3 = s2 + v3;
    lds[tid] = s3;
    __syncthreads();
    for (int d = 1; d < 256; d <<= 1) {
        int t = 0;
        if (tid >= d) t = lds[tid - d];
        __syncthreads();
        lds[tid] += t;
        __syncthreads();
    }
    int run = (tid > 0) ? lds[tid - 1] : 0;
    if (base + 0 < nb) { int o = bs[base + 0]; bs[base + 0] = run; run += o; }
    if (base + 1 < nb) { int o = bs[base + 1]; bs[base + 1] = run; run += o; }
    if (base + 2 < nb) { int o = bs[base + 2]; bs[base + 2] = run; run += o; }
    if (base + 3 < nb) { int o = bs[base + 3]; bs[base + 3] = run; run += o; }
}

// scan3: add exclusive block offsets
__global__ __launch_bounds__(256) void scan3_kernel(
    int* __restrict__ out, const int* __restrict__ bs, int n)
{
    int b = blockIdx.x;
    if (b == 0) return;
    int add  = bs[b];
    int base = b * 1024 + threadIdx.x * 4;
    if (base + 0 < n) out[base + 1] += add;
    if (base + 1 < n) out[base + 2] += add;
    if (base + 2 < n) out[base + 3] += add;
    if (base + 3 < n) out[base + 4] += add;
}

// scatter edges into row-sorted order; cursor starts as a copy of off
__global__ __launch_bounds__(256) void scatter_kernel(
    const int* __restrict__ rows, const int* __restrict__ cols,
    const float* __restrict__ vals, int* __restrict__ cursor,
    int2* __restrict__ edges, int nnz)
{
    int e = blockIdx.x * blockDim.x + threadIdx.x;
    if (e >= nnz) return;
    int r   = rows[e];
    int pos = atomicAdd(&cursor[r], 1);
    edges[pos] = make_int2(cols[e], __float_as_int(vals[e]));
}

// ===========================================================================
// CSR SpMM: 32 lanes per output row, float4 per lane, register accumulate,
// one coalesced 512B store per row. No atomics, no pre-zeroing.
// ===========================================================================
__global__ __launch_bounds__(256) void spmm_csr_kernel(
    const int* __restrict__ off, const int2* __restrict__ edges,
    const float* __restrict__ x, float* __restrict__ out, int n_rows)
{
    int t    = blockIdx.x * blockDim.x + threadIdx.x;
    int row  = t >> 5;
    int lane = t & 31;
    if (row >= n_rows) return;
    int beg = off[row], end = off[row + 1];
    float4 acc = make_float4(0.f, 0.f, 0.f, 0.f);
    for (int k = beg; k < end; ++k) {
        int2 e  = edges[k];
        float v = __int_as_float(e.y);
        const float4 xv = *reinterpret_cast<const float4*>(
            x + (size_t)e.x * DIM + lane * 4);
        acc.x += v * xv.x;
        acc.y += v * xv.y;
        acc.z += v * xv.z;
        acc.w += v * xv.w;
    }
    *reinterpret_cast<float4*>(out + (size_t)row * DIM + lane * 4) = acc;
}

// ===========================================================================
// Fused: out = relu( concat([ho, cur], axis=1) @ W + b )
// Block: 256 threads, tile 64 rows x 128 cols. In-place-safe on HO.
// ===========================================================================
__global__ __launch_bounds__(256) void fused_gemm_relu_kernel(
    const float* __restrict__ HO, const float* __restrict__ CUR,
    const float* __restrict__ W, const float* __restrict__ bias,
    float* __restrict__ out, int M)
{
    __shared__ float As[64][64];
    __shared__ float Ws[64][128];

    int tid  = threadIdx.x;
    int row0 = blockIdx.x * 64;

    int cx = tid & 31;   // col group: cols cx*4 .. cx*4+3
    int ry = tid >> 5;   // row group: rows ry*8 .. ry*8+7

    float4 acc[8];
#pragma unroll
    for (int i = 0; i < 8; ++i) acc[i] = make_float4(0.f, 0.f, 0.f, 0.f);

    for (int kb = 0; kb < 4; ++kb) {
        const float* src = (kb < 2) ? HO : CUR;
        int colbase = (kb & 1) * 64;

        {
            int r  = tid >> 4;   // 0..15
            int c4 = tid & 15;   // 0..15
#pragma unroll
            for (int it = 0; it < 4; ++it) {
                int rr   = r + it * 16;
                int grow = row0 + rr;
                float4 v = make_float4(0.f, 0.f, 0.f, 0.f);
                if (grow < M)
                    v = *reinterpret_cast<const float4*>(
                        src + (size_t)grow * DIM + colbase + c4 * 4);
                *reinterpret_cast<float4*>(&As[rr][c4 * 4]) = v;
            }
        }
        {
            int r  = tid >> 5;   // 0..7
            int c4 = tid & 31;   // 0..31
#pragma unroll
            for (int it = 0; it < 8; ++it) {
                int rr = r + it * 8;
                float4 v = *reinterpret_cast<const float4*>(
                    W + (size_t)(kb * 64 + rr) * DIM + c4 * 4);
                *reinterpret_cast<float4*>(&Ws[rr][c4 * 4]) = v;
            }
        }
        __syncthreads();

#pragma unroll 16
        for (int k = 0; k < 64; ++k) {
            float4 wv = *reinterpret_cast<const float4*>(&Ws[k][cx * 4]);
#pragma unroll
            for (int i = 0; i < 8; ++i) {
                float a = As[ry * 8 + i][k];
                acc[i].x += a * wv.x;
                acc[i].y += a * wv.y;
                acc[i].z += a * wv.z;
                acc[i].w += a * wv.w;
            }
        }
        __syncthreads();
    }

    float4 bv = *reinterpret_cast<const float4*>(bias + cx * 4);
#pragma unroll
    for (int i = 0; i < 8; ++i) {
        int grow = row0 + ry * 8 + i;
        if (grow < M) {
            float4 r;
            r.x = fmaxf(acc[i].x + bv.x, 0.f);
            r.y = fmaxf(acc[i].y + bv.y, 0.f);
            r.z = fmaxf(acc[i].z + bv.z, 0.f);
            r.w = fmaxf(acc[i].w + bv.w, 0.f);
            *reinterpret_cast<float4*>(out + (size_t)grow * DIM + cx * 4) = r;
        }
    }
}

extern "C" void kernel_launch(void* const* d_in, const int* in_sizes, int n_in,
                              void* d_out, int out_size, void* d_ws, size_t ws_size,
                              hipStream_t stream) {
    const float* ufea    = (const float*)d_in[0];
    const float* vfea    = (const float*)d_in[1];
    const int*   uv_rows = (const int*)d_in[2];
    const int*   uv_cols = (const int*)d_in[3];
    const float* uv_vals = (const float*)d_in[4];
    const int*   vu_rows = (const int*)d_in[5];
    const int*   vu_cols = (const int*)d_in[6];
    const float* vu_vals = (const float*)d_in[7];
    const float* user_W  = (const float*)d_in[8];   // [2, 256, 128]
    const float* user_b  = (const float*)d_in[9];   // [2, 128]
    const float* item_W  = (const float*)d_in[10];
    const float* item_b  = (const float*)d_in[11];

    const int nnz = in_sizes[2];

    float* out_user = (float*)d_out;                       // [U,128]
    float* out_item = out_user + (size_t)N_USERS * DIM;    // [I,128]

    const size_t UD = (size_t)N_USERS * DIM;   // 25.6M floats
    const size_t ID = (size_t)N_ITEMS * DIM;   // 12.8M floats

    // ---- workspace layout (floats/ints, 16B-aligned chunks) ----
    char* p = (char*)d_ws;
    auto alloc = [&](size_t bytes) {
        char* q = p;
        p += (bytes + 15) & ~(size_t)15;
        return q;
    };
    float* U0 = (float*)alloc(UD * 4);
    float* V0 = (float*)alloc(ID * 4);
    float* V1 = (float*)alloc(ID * 4);
    int*  uv_off = (int*)alloc((N_USERS + 1) * 4);
    int*  uv_cur = (int*)alloc((N_USERS + 1) * 4);
    int2* uv_edg = (int2*)alloc((size_t)nnz * 8);
    int*  vu_off = (int*)alloc((N_ITEMS + 1) * 4);
    int*  vu_cur = (int*)alloc((N_ITEMS + 1) * 4);
    int2* vu_edg = (int2*)alloc((size_t)nnz * 8);
    int*  bsums  = (int*)alloc(1024 * 4);

    // reuse output regions as scratch until the final GEMMs
    float* U1 = out_user;
    float* V2 = out_item;

    // ---- build CSR for both graphs ----
    auto build_csr = [&](const int* rows, const int* cols, const float* vals,
                         int n_rows, int* off, int* cursor, int2* edges) {
        int eb = (nnz + 255) / 256;
        int nb = (n_rows + 1023) / 1024;
        hipMemsetAsync(cursor, 0, (size_t)(n_rows + 1) * 4, stream);
        hist_kernel<<<eb, 256, 0, stream>>>(rows, cursor, nnz);
        scan1_kernel<<<nb, 256, 0, stream>>>(cursor, off, bsums, n_rows);
        scan2_kernel<<<1, 256, 0, stream>>>(bsums, nb);
        scan3_kernel<<<nb, 256, 0, stream>>>(off, bsums, n_rows);
        hipMemcpyAsync(cursor, off, (size_t)n_rows * 4,
                       hipMemcpyDeviceToDevice, stream);
        scatter_kernel<<<eb, 256, 0, stream>>>(rows, cols, vals, cursor, edges, nnz);
    };
    build_csr(uv_rows, uv_cols, uv_vals, N_USERS, uv_off, uv_cur, uv_edg);
    build_csr(vu_rows, vu_cols, vu_vals, N_ITEMS, vu_off, vu_cur, vu_edg);

    auto spmm_uv = [&](const float* x, float* out) {  // [U] out, gathers items-side x
        int blocks = (int)(((size_t)N_USERS * 32 + 255) / 256);
        spmm_csr_kernel<<<blocks, 256, 0, stream>>>(uv_off, uv_edg, x, out, N_USERS);
    };
    auto spmm_vu = [&](const float* x, float* out) {  // [I] out
        int blocks = (int)(((size_t)N_ITEMS * 32 + 255) / 256);
        spmm_csr_kernel<<<blocks, 256, 0, stream>>>(vu_off, vu_edg, x, out, N_ITEMS);
    };
    auto gemm = [&](const float* ho, const float* cur, const float* Wl,
                    const float* bl, float* out, int M) {
        fused_gemm_relu_kernel<<<(M + 63) / 64, 256, 0, stream>>>(ho, cur, Wl, bl, out, M);
    };

    // ---------------- layer 0 (cur_u = ufea, cur_v = vfea) ----------------
    spmm_vu(ufea, V0);            // TI  = spmm(vu, cur_u)  [I]
    spmm_uv(vfea, U0);            // TU  = spmm(uv, cur_v)  [U]
    spmm_vu(U0,   V1);            // HV  = spmm(vu, TU)     [I]
    spmm_uv(V0,   U0);            // HU  = spmm(uv, TI)     [U]  (TU consumed)
    gemm(U0, ufea, user_W,                user_b,       U0, N_USERS);  // in-place
    gemm(V1, vfea, item_W,                item_b,       V1, N_ITEMS);  // in-place

    // ---------------- layer 1 (cur_u = U0, cur_v = V1) --------------------
    spmm_vu(U0, V0);              // TI'
    spmm_uv(V1, U1);              // TU'  (scratch = out_user)
    spmm_vu(U1, V2);              // HV'  (scratch = out_item)
    spmm_uv(V0, U1);              // HU'  (overwrites TU', already consumed)
    gemm(U1, U0, user_W + 2 * DIM * DIM, user_b + DIM, out_user, N_USERS); // in-place
    gemm(V2, V1, item_W + 2 * DIM * DIM, item_b + DIM, out_item, N_ITEMS); // in-place
}

// Round 3
// 1584.909 us; speedup vs baseline: 17.2585x; 1.4565x over previous
//
#include <hip/hip_runtime.h>

#define DIM 128
#define N_USERS 200000
#define N_ITEMS 100000

typedef __attribute__((ext_vector_type(8))) _Float16 half8;
typedef __attribute__((ext_vector_type(4))) _Float16 half4v;
typedef __attribute__((ext_vector_type(4))) float f32x4;

// ===========================================================================
// CSR build: histogram -> 3-phase exclusive scan -> scatter
// ===========================================================================

__global__ __launch_bounds__(256) void hist_kernel(
    const int* __restrict__ rows, int* __restrict__ counts, int nnz)
{
    int e = blockIdx.x * blockDim.x + threadIdx.x;
    if (e < nnz) atomicAdd(&counts[rows[e]], 1);
}

__global__ __launch_bounds__(256) void scan1_kernel(
    const int* __restrict__ in, int* __restrict__ out,
    int* __restrict__ blockSums, int n)
{
    __shared__ int lds[256];
    int tid  = threadIdx.x;
    int base = blockIdx.x * 1024 + tid * 4;
    int v0 = (base + 0 < n) ? in[base + 0] : 0;
    int v1 = (base + 1 < n) ? in[base + 1] : 0;
    int v2 = (base + 2 < n) ? in[base + 2] : 0;
    int v3 = (base + 3 < n) ? in[base + 3] : 0;
    int s1 = v0 + v1, s2 = s1 + v2, s3 = s2 + v3;
    lds[tid] = s3;
    __syncthreads();
    for (int d = 1; d < 256; d <<= 1) {
        int t = 0;
        if (tid >= d) t = lds[tid - d];
        __syncthreads();
        lds[tid] += t;
        __syncthreads();
    }
    int excl = (tid > 0) ? lds[tid - 1] : 0;
    if (base + 0 < n) out[base + 1] = excl + v0;
    if (base + 1 < n) out[base + 2] = excl + s1;
    if (base + 2 < n) out[base + 3] = excl + s2;
    if (base + 3 < n) out[base + 4] = excl + s3;
    if (tid == 255) blockSums[blockIdx.x] = lds[255];
    if (blockIdx.x == 0 && tid == 0) out[0] = 0;
}

__global__ __launch_bounds__(256) void scan2_kernel(int* __restrict__ bs, int nb)
{
    __shared__ int lds[256];
    int tid  = threadIdx.x;
    int base = tid * 4;
    int v0 = (base + 0 < nb) ? bs[base + 0] : 0;
    int v1 = (base + 1 < nb) ? bs[base + 1] : 0;
    int v2 = (base + 2 < nb) ? bs[base + 2] : 0;
    int v3 = (base + 3 < nb) ? bs[base + 3] : 0;
    int s1 = v0 + v1, s2 = s1 + v2, s3 = s2 + v3;
    lds[tid] = s3;
    __syncthreads();
    for (int d = 1; d < 256; d <<= 1) {
        int t = 0;
        if (tid >= d) t = lds[tid - d];
        __syncthreads();
        lds[tid] += t;
        __syncthreads();
    }
    int run = (tid > 0) ? lds[tid - 1] : 0;
    if (base + 0 < nb) { int o = bs[base + 0]; bs[base + 0] = run; run += o; }
    if (base + 1 < nb) { int o = bs[base + 1]; bs[base + 1] = run; run += o; }
    if (base + 2 < nb) { int o = bs[base + 2]; bs[base + 2] = run; run += o; }
    if (base + 3 < nb) { int o = bs[base + 3]; bs[base + 3] = run; run += o; }
}

__global__ __launch_bounds__(256) void scan3_kernel(
    int* __restrict__ out, const int* __restrict__ bs, int n)
{
    int b = blockIdx.x;
    if (b == 0) return;
    int add  = bs[b];
    int base = b * 1024 + threadIdx.x * 4;
    if (base + 0 < n) out[base + 1] += add;
    if (base + 1 < n) out[base + 2] += add;
    if (base + 2 < n) out[base + 3] += add;
    if (base + 3 < n) out[base + 4] += add;
}

__global__ __launch_bounds__(256) void scatter_kernel(
    const int* __restrict__ rows, const int* __restrict__ cols,
    const float* __restrict__ vals, int* __restrict__ cursor,
    int2* __restrict__ edges, int nnz)
{
    int e = blockIdx.x * blockDim.x + threadIdx.x;
    if (e >= nnz) return;
    int r   = rows[e];
    int pos = atomicAdd(&cursor[r], 1);
    edges[pos] = make_int2(cols[e], __float_as_int(vals[e]));
}

// ===========================================================================
// fp32 -> fp16 table conversion (8 elems / thread)
// ===========================================================================
__global__ __launch_bounds__(256) void conv_f16_kernel(
    const float* __restrict__ src, _Float16* __restrict__ dst, int n8)
{
    int t = blockIdx.x * blockDim.x + threadIdx.x;
    if (t >= n8) return;
    const float4* s = reinterpret_cast<const float4*>(src) + (size_t)t * 2;
    float4 a = s[0], b = s[1];
    half8 h;
    h[0] = (_Float16)a.x; h[1] = (_Float16)a.y;
    h[2] = (_Float16)a.z; h[3] = (_Float16)a.w;
    h[4] = (_Float16)b.x; h[5] = (_Float16)b.y;
    h[6] = (_Float16)b.z; h[7] = (_Float16)b.w;
    reinterpret_cast<half8*>(dst)[t] = h;
}

// W [2][256][128] fp32  ->  Wt [2][128][256] fp16 (transposed per layer)
__global__ __launch_bounds__(256) void transposeW_kernel(
    const float* __restrict__ W, _Float16* __restrict__ Wt)
{
    int t = blockIdx.x * blockDim.x + threadIdx.x;   // 0..65535
    int l = t >> 15;
    int r = t & 32767;
    int k = r >> 7;
    int n = r & 127;
    Wt[(size_t)l * 32768 + n * 256 + k] = (_Float16)W[t];
}

// ===========================================================================
// CSR SpMM fp16: 16 lanes per row, 16B gathers, fp32 accum, fp16 store
// ===========================================================================
__global__ __launch_bounds__(256) void spmm_csr_f16_kernel(
    const int* __restrict__ off, const int2* __restrict__ edges,
    const _Float16* __restrict__ x, _Float16* __restrict__ out, int n_rows)
{
    int t    = blockIdx.x * blockDim.x + threadIdx.x;
    int row  = t >> 4;
    int lane = t & 15;
    if (row >= n_rows) return;
    int beg = off[row], end = off[row + 1];
    float acc[8] = {0.f, 0.f, 0.f, 0.f, 0.f, 0.f, 0.f, 0.f};
    for (int k = beg; k < end; ++k) {
        int2 e  = edges[k];
        float v = __int_as_float(e.y);
        half8 xv = *reinterpret_cast<const half8*>(x + (size_t)e.x * DIM + lane * 8);
#pragma unroll
        for (int i = 0; i < 8; ++i) acc[i] += v * (float)xv[i];
    }
    half8 o;
#pragma unroll
    for (int i = 0; i < 8; ++i) o[i] = (_Float16)acc[i];
    *reinterpret_cast<half8*>(out + (size_t)row * DIM + lane * 8) = o;
}

// ===========================================================================
// MFMA GEMM: out = relu( concat([HO, CUR]) @ W + b ), fp16 in, fp32 acc.
// Swapped operands: mfma(Wt_frag, A_frag) -> each lane holds 4 consecutive
// output features of one row -> vectorized stores. Block 256 = 4 waves.
// ===========================================================================
template<int OUT_F32>
__global__ __launch_bounds__(256) void gemm_f16_kernel(
    const _Float16* __restrict__ HO, const _Float16* __restrict__ CUR,
    const _Float16* __restrict__ Wt,   // [128][256] fp16
    const float* __restrict__ bias,    // [128] fp32
    float* __restrict__ outF, _Float16* __restrict__ outH, int M)
{
    int tid  = threadIdx.x;
    int wave = tid >> 6;
    int l    = tid & 63;
    int m    = l & 15;        // A-row within wave tile (= B-frag col = D col)
    int kg   = l >> 4;        // 0..3 k-group
    int row  = blockIdx.x * 64 + wave * 16 + m;
    int rr   = min(row, M - 1);

    half8 afrag[8];
#pragma unroll
    for (int kk = 0; kk < 8; ++kk) {
        const _Float16* src = (kk < 4) ? HO : CUR;
        int k0 = (kk & 3) * 32 + kg * 8;
        afrag[kk] = *reinterpret_cast<const half8*>(src + (size_t)rr * DIM + k0);
    }

#pragma unroll
    for (int j = 0; j < 8; ++j) {
        f32x4 acc = {0.f, 0.f, 0.f, 0.f};
#pragma unroll
        for (int kk = 0; kk < 8; ++kk) {
            half8 wfrag = *reinterpret_cast<const half8*>(
                Wt + (size_t)(j * 16 + m) * 256 + kk * 32 + kg * 8);
            acc = __builtin_amdgcn_mfma_f32_16x16x32_f16(wfrag, afrag[kk], acc, 0, 0, 0);
        }
        int n0 = j * 16 + kg * 4;
        float4 bv = *reinterpret_cast<const float4*>(bias + n0);
        float o0 = fmaxf(acc[0] + bv.x, 0.f);
        float o1 = fmaxf(acc[1] + bv.y, 0.f);
        float o2 = fmaxf(acc[2] + bv.z, 0.f);
        float o3 = fmaxf(acc[3] + bv.w, 0.f);
        if (row < M) {
            if (OUT_F32) {
                float4 st = make_float4(o0, o1, o2, o3);
                *reinterpret_cast<float4*>(outF + (size_t)row * DIM + n0) = st;
            } else {
                half4v st;
                st[0] = (_Float16)o0; st[1] = (_Float16)o1;
                st[2] = (_Float16)o2; st[3] = (_Float16)o3;
                *reinterpret_cast<half4v*>(outH + (size_t)row * DIM + n0) = st;
            }
        }
    }
}

extern "C" void kernel_launch(void* const* d_in, const int* in_sizes, int n_in,
                              void* d_out, int out_size, void* d_ws, size_t ws_size,
                              hipStream_t stream) {
    const float* ufea    = (const float*)d_in[0];
    const float* vfea    = (const float*)d_in[1];
    const int*   uv_rows = (const int*)d_in[2];
    const int*   uv_cols = (const int*)d_in[3];
    const float* uv_vals = (const float*)d_in[4];
    const int*   vu_rows = (const int*)d_in[5];
    const int*   vu_cols = (const int*)d_in[6];
    const float* vu_vals = (const float*)d_in[7];
    const float* user_W  = (const float*)d_in[8];   // [2, 256, 128]
    const float* user_b  = (const float*)d_in[9];   // [2, 128]
    const float* item_W  = (const float*)d_in[10];
    const float* item_b  = (const float*)d_in[11];

    const int nnz = in_sizes[2];

    float* out_user = (float*)d_out;
    float* out_item = out_user + (size_t)N_USERS * DIM;

    const size_t UD = (size_t)N_USERS * DIM;
    const size_t ID = (size_t)N_ITEMS * DIM;

    char* p = (char*)d_ws;
    auto alloc = [&](size_t bytes) {
        char* q = p;
        p += (bytes + 255) & ~(size_t)255;
        return q;
    };
    _Float16* Uf = (_Float16*)alloc(UD * 2);
    _Float16* Vf = (_Float16*)alloc(ID * 2);
    _Float16* Ua = (_Float16*)alloc(UD * 2);
    _Float16* Ub = (_Float16*)alloc(UD * 2);
    _Float16* Va = (_Float16*)alloc(ID * 2);
    _Float16* Vb = (_Float16*)alloc(ID * 2);
    _Float16* Vc = (_Float16*)alloc(ID * 2);
    _Float16* Wt_user = (_Float16*)alloc((size_t)2 * 128 * 256 * 2);
    _Float16* Wt_item = (_Float16*)alloc((size_t)2 * 128 * 256 * 2);
    int*  uv_off = (int*)alloc((N_USERS + 1) * 4);
    int*  uv_cur = (int*)alloc((N_USERS + 1) * 4);
    int2* uv_edg = (int2*)alloc((size_t)nnz * 8);
    int*  vu_off = (int*)alloc((N_ITEMS + 1) * 4);
    int*  vu_cur = (int*)alloc((N_ITEMS + 1) * 4);
    int2* vu_edg = (int2*)alloc((size_t)nnz * 8);
    int*  bsums  = (int*)alloc(1024 * 4);

    conv_f16_kernel<<<(int)((UD / 8 + 255) / 256), 256, 0, stream>>>(ufea, Uf, (int)(UD / 8));
    conv_f16_kernel<<<(int)((ID / 8 + 255) / 256), 256, 0, stream>>>(vfea, Vf, (int)(ID / 8));
    transposeW_kernel<<<256, 256, 0, stream>>>(user_W, Wt_user);
    transposeW_kernel<<<256, 256, 0, stream>>>(item_W, Wt_item);

    auto build_csr = [&](const int* rows, const int* cols, const float* vals,
                         int n_rows, int* off, int* cursor, int2* edges) {
        int eb = (nnz + 255) / 256;
        int nb = (n_rows + 1023) / 1024;
        hipMemsetAsync(cursor, 0, (size_t)(n_rows + 1) * 4, stream);
        hist_kernel<<<eb, 256, 0, stream>>>(rows, cursor, nnz);
        scan1_kernel<<<nb, 256, 0, stream>>>(cursor, off, bsums, n_rows);
        scan2_kernel<<<1, 256, 0, stream>>>(bsums, nb);
        scan3_kernel<<<nb, 256, 0, stream>>>(off, bsums, n_rows);
        hipMemcpyAsync(cursor, off, (size_t)n_rows * 4,
                       hipMemcpyDeviceToDevice, stream);
        scatter_kernel<<<eb, 256, 0, stream>>>(rows, cols, vals, cursor, edges, nnz);
    };
    build_csr(uv_rows, uv_cols, uv_vals, N_USERS, uv_off, uv_cur, uv_edg);
    build_csr(vu_rows, vu_cols, vu_vals, N_ITEMS, vu_off, vu_cur, vu_edg);

    auto spmm_uv = [&](const _Float16* x, _Float16* out) {
        int blocks = (int)(((size_t)N_USERS * 16 + 255) / 256);
        spmm_csr_f16_kernel<<<blocks, 256, 0, stream>>>(uv_off, uv_edg, x, out, N_USERS);
    };
    auto spmm_vu = [&](const _Float16* x, _Float16* out) {
        int blocks = (int)(((size_t)N_ITEMS * 16 + 255) / 256);
        spmm_csr_f16_kernel<<<blocks, 256, 0, stream>>>(vu_off, vu_edg, x, out, N_ITEMS);
    };
    auto gemm_h = [&](const _Float16* ho, const _Float16* cur, const _Float16* Wt,
                      const float* bl, _Float16* out, int M) {
        gemm_f16_kernel<0><<<(M + 63) / 64, 256, 0, stream>>>(ho, cur, Wt, bl,
                                                              (float*)nullptr, out, M);
    };
    auto gemm_f = [&](const _Float16* ho, const _Float16* cur, const _Float16* Wt,
                      const float* bl, float* out, int M) {
        gemm_f16_kernel<1><<<(M + 63) / 64, 256, 0, stream>>>(ho, cur, Wt, bl,
                                                              out, (_Float16*)nullptr, M);
    };

    // ---------------- layer 0 (cur_u = Uf, cur_v = Vf) ----------------
    spmm_vu(Uf, Va);                  // TI  [I]
    spmm_uv(Vf, Ua);                  // TU  [U]
    spmm_vu(Ua, Vb);                  // HV  [I]  (TU consumed)
    spmm_uv(Va, Ub);                  // HU  [U]  (TI consumed)
    gemm_h(Ub, Uf, Wt_user, user_b, Ua, N_USERS);   // learn_user -> Ua
    gemm_h(Vb, Vf, Wt_item, item_b, Va, N_ITEMS);   // learn_item -> Va

    // ---------------- layer 1 (cur_u = Ua, cur_v = Va) -----------------
    spmm_vu(Ua, Vb);                  // TI'
    spmm_uv(Va, Ub);                  // TU'
    spmm_vu(Ub, Vc);                  // HV'  (TU' consumed)
    spmm_uv(Vb, Ub);                  // HU'  (overwrites TU', already consumed)
    gemm_f(Ub, Ua, Wt_user + 32768, user_b + DIM, out_user, N_USERS);
    gemm_f(Vc, Va, Wt_item + 32768, item_b + DIM, out_item, N_ITEMS);
}